// Round 7
// baseline (179.748 us; speedup 1.0000x reference)
//
#include <hip/hip_runtime.h>
#include <hip/hip_bf16.h>

// (B,T,D,H) = (4,2048,384,6), HD=64. Inputs/output f32; intermediates bf16.
#define BB   4
#define TT   2048
#define DDIM 384
#define HH   6
#define HD   64
#define BT   (BB*TT)
#define QKVC (3*DDIM)

typedef __attribute__((ext_vector_type(4))) short short4v;
typedef __attribute__((ext_vector_type(8))) short short8v;
typedef __attribute__((ext_vector_type(4))) float float4v;
typedef unsigned short u16;

static __device__ __forceinline__ u16 f2bu(float f) {
    __hip_bfloat16 h = __float2bfloat16(f);
    return __builtin_bit_cast(u16, h);
}

static __device__ __forceinline__ short8v ld_frag(const u16* p) {
    short4v a = *(const short4v*)p;
    short4v b = *(const short4v*)(p + 4);
    return __builtin_shufflevector(a, b, 0, 1, 2, 3, 4, 5, 6, 7);
}

static __device__ __forceinline__ void st8(u16* p, uint4 v) {
    *(uint2*)p       = make_uint2(v.x, v.y);
    *(uint2*)(p + 4) = make_uint2(v.z, v.w);
}

#define MFMA16(a, b, c) __builtin_amdgcn_mfma_f32_16x16x32_bf16((a), (b), (c), 0, 0, 0)

// ---------------------------------------------------------------------------
// K0 (merged prep): blocks [0,108): wqkv^T ; [108,144): wproj^T ; [144,912):
// x -> bf16 cast.
// ---------------------------------------------------------------------------
__global__ __launch_bounds__(256) void prep_kernel(
    const float* __restrict__ wqkv, const float* __restrict__ wproj,
    const float* __restrict__ x,
    u16* __restrict__ wqkvT, u16* __restrict__ wprojT, u16* __restrict__ xb)
{
    const int bid = blockIdx.x;
    const int t = threadIdx.x;
    if (bid >= 144) {
        size_t base = (size_t)(bid - 144) * 4096 + (size_t)t * 16;
        const float* gp = x + base;
        __align__(16) u16 tmp[16];
        #pragma unroll
        for (int u = 0; u < 4; ++u) {
            float4 v = *(const float4*)(gp + 4 * u);
            tmp[4 * u + 0] = f2bu(v.x); tmp[4 * u + 1] = f2bu(v.y);
            tmp[4 * u + 2] = f2bu(v.z); tmp[4 * u + 3] = f2bu(v.w);
        }
        *(uint4*)(xb + base)     = *(const uint4*)tmp;
        *(uint4*)(xb + base + 8) = *(const uint4*)(tmp + 8);
        return;
    }
    const float* in; u16* out; int K, C, c0, k0;
    if (bid < 108) { in = wqkv;  out = wqkvT;  K = DDIM; C = QKVC;
                     c0 = (bid % 18) * 64; k0 = (bid / 18) * 64; }
    else           { int b2 = bid - 108; in = wproj; out = wprojT; K = DDIM; C = DDIM;
                     c0 = (b2 % 6) * 64; k0 = (b2 / 6) * 64; }
    __shared__ float tr[64][65];
    {
        int kr = t >> 2, cb = (t & 3) * 16;
        const float* gp = in + (size_t)(k0 + kr) * C + c0 + cb;
        #pragma unroll
        for (int u = 0; u < 4; ++u) {
            float4 v = *(const float4*)(gp + 4 * u);
            tr[cb + 4 * u + 0][kr] = v.x;
            tr[cb + 4 * u + 1][kr] = v.y;
            tr[cb + 4 * u + 2][kr] = v.z;
            tr[cb + 4 * u + 3][kr] = v.w;
        }
    }
    __syncthreads();
    {
        int c = t >> 2, kb = (t & 3) * 16;
        __align__(16) u16 tmp[16];
        #pragma unroll
        for (int u = 0; u < 16; ++u) tmp[u] = f2bu(tr[c][kb + u]);
        u16* op = out + (size_t)(c0 + c) * K + k0 + kb;
        *(uint4*)op       = *(const uint4*)tmp;
        *(uint4*)(op + 8) = *(const uint4*)(tmp + 8);
    }
}

// ---------------------------------------------------------------------------
// K1: qkv = xb @ wqkvT, RoPE fused in epilogue.
//   q,k -> [bh][t][d] bf16 ; v -> TRANSPOSED [bh][d][t] bf16.
// ---------------------------------------------------------------------------
__global__ __launch_bounds__(256) void qkv_rope_kernel(
    const u16* __restrict__ xb, const u16* __restrict__ wt,
    const float* __restrict__ cs, const float* __restrict__ sn,
    u16* __restrict__ qb, u16* __restrict__ kb, u16* __restrict__ vtb)
{
    __shared__ __align__(16) u16 xs[2][64][68];
    __shared__ __align__(16) u16 ws[2][64][68];
    const int t = threadIdx.x;
    const int wv = t >> 6, lane = t & 63, quad = lane >> 4, lo = lane & 15;
    const int r0 = blockIdx.y * 64;
    const int c0 = blockIdx.x * 64;
    const int sr = t >> 3, sd = (t & 7) * 8;

    st8(&xs[0][sr][sd],      *(const uint4*)(xb + (size_t)(r0 + sr) * DDIM + sd));
    st8(&xs[0][sr + 32][sd], *(const uint4*)(xb + (size_t)(r0 + sr + 32) * DDIM + sd));
    st8(&ws[0][sr][sd],      *(const uint4*)(wt + (size_t)(c0 + sr) * DDIM + sd));
    st8(&ws[0][sr + 32][sd], *(const uint4*)(wt + (size_t)(c0 + sr + 32) * DDIM + sd));
    __syncthreads();

    float4v acc[4] = {};
    for (int kk = 0; kk < 6; ++kk) {
        const int cur = kk & 1, nxt = cur ^ 1;
        const int kkn = (kk < 5 ? kk + 1 : 5) * 64;
        uint4 xp0 = *(const uint4*)(xb + (size_t)(r0 + sr) * DDIM + kkn + sd);
        uint4 xp1 = *(const uint4*)(xb + (size_t)(r0 + sr + 32) * DDIM + kkn + sd);
        uint4 wp0 = *(const uint4*)(wt + (size_t)(c0 + sr) * DDIM + kkn + sd);
        uint4 wp1 = *(const uint4*)(wt + (size_t)(c0 + sr + 32) * DDIM + kkn + sd);

        #pragma unroll
        for (int kf = 0; kf < 2; ++kf) {
            short8v a = ld_frag(&xs[cur][16 * wv + lo][kf * 32 + quad * 8]);
            #pragma unroll
            for (int nt = 0; nt < 4; ++nt) {
                short8v b = ld_frag(&ws[cur][nt * 16 + lo][kf * 32 + quad * 8]);
                acc[nt] = MFMA16(a, b, acc[nt]);
            }
        }
        st8(&xs[nxt][sr][sd], xp0);
        st8(&xs[nxt][sr + 32][sd], xp1);
        st8(&ws[nxt][sr][sd], wp0);
        st8(&ws[nxt][sr + 32][sd], wp1);
        __syncthreads();
    }

    const int sec = blockIdx.x / 6;     // 0=q, 1=k, 2=v
    const int h   = blockIdx.x % 6;
    const int rbase = r0 + 16 * wv + 4 * quad;
    const int bidx  = r0 >> 11;
    const int tbase = rbase & (TT - 1);

    if (sec == 2) {
        #pragma unroll
        for (int nt = 0; nt < 4; ++nt) {
            int d = nt * 16 + lo;
            unsigned a0 = f2bu(acc[nt][0]) | ((unsigned)f2bu(acc[nt][1]) << 16);
            unsigned a1 = f2bu(acc[nt][2]) | ((unsigned)f2bu(acc[nt][3]) << 16);
            u16* gp = vtb + ((size_t)(bidx * HH + h) * HD + d) * TT + tbase;
            *(uint2*)gp = make_uint2(a0, a1);
        }
    } else {
        u16* dst = (sec == 0) ? qb : kb;
        #pragma unroll
        for (int np = 0; np < 2; ++np) {
            #pragma unroll
            for (int r = 0; r < 4; ++r) {
                int tpos = tbase + r;
                int ci = np * 16 + lo;
                float cv = cs[tpos * 32 + ci];
                float sv = sn[tpos * 32 + ci];
                float x1 = acc[np][r], x2 = acc[np + 2][r];
                u16* gp = dst + ((size_t)(bidx * HH + h) * TT + tpos) * HD;
                gp[ci]      = f2bu(x1 * cv - x2 * sv);
                gp[ci + 32] = f2bu(x2 * cv + x1 * sv);
            }
        }
    }
}

// ---------------------------------------------------------------------------
// K2: MFMA flash attention, split-K x2, occupancy-optimized:
//   - single-buffered K/V staging (LDS 26.6 KB -> 6 blocks/CU, 24 waves/CU)
//   - grid (bh, q, half) = 24x32x2 = 1536 blocks so 6/CU are actually resident
//   - S^T = K.Q^T; P via wave-private LDS (b64 writes / b128 reads)
//   - l-sum via MFMA with all-ones B-frag (no VALU adds, no epilogue shuffles)
//   - unshifted exp => split halves merge by simple addition (merge_kernel)
//   - partial O (f32) and l (f32) to workspace
// ---------------------------------------------------------------------------
__global__ __launch_bounds__(256, 6) void attn_kernel(
    const u16* __restrict__ qb, const u16* __restrict__ kb, const u16* __restrict__ vtb,
    const float* __restrict__ bias, float* __restrict__ opart, float* __restrict__ lws)
{
    __shared__ __align__(16) u16 ks[64][68];
    __shared__ __align__(16) u16 vt[64][68];
    __shared__ __align__(16) u16 ps[4][16][72];

    const int t = threadIdx.x;
    const int wv = t >> 6, lane = t & 63, quad = lane >> 4, lo = lane & 15;
    const int bh = blockIdx.x;
    const int b = bh / HH, h = bh % HH;
    const int q0 = blockIdx.y * 64;
    const int half = blockIdx.z;
    const int kbase0 = half * (TT / 2);
    const int qrow = q0 + 16 * wv + lo;           // q-row owned by this lane

    // Q fragments (B-operand of S^T): straight from global
    const u16* qbase = qb + ((size_t)bh * TT + qrow) * HD + quad * 8;
    short8v aq0 = __builtin_bit_cast(short8v, *(const uint4*)qbase);
    short8v aq1 = __builtin_bit_cast(short8v, *(const uint4*)(qbase + 32));

    const int sr = t >> 3, sd = (t & 7) * 8;
    const u16* kbbase = kb + ((size_t)bh * TT + kbase0) * HD;
    const u16* vtbase = vtb + (size_t)bh * HD * TT + kbase0;
    const float* brow = bias + (size_t)qrow * TT + kbase0 + 4 * quad;

    // all-ones bf16 B-fragment for the l-sum MFMA (layout-invariant)
    const short8v bones = { 0x3F80, 0x3F80, 0x3F80, 0x3F80,
                            0x3F80, 0x3F80, 0x3F80, 0x3F80 };

    // prefetch tile 0 into regs
    uint4 kp0 = *(const uint4*)(kbbase + (size_t)sr * HD + sd);
    uint4 kp1 = *(const uint4*)(kbbase + (size_t)(sr + 32) * HD + sd);
    uint4 vp0 = *(const uint4*)(vtbase + (size_t)sr * TT + sd);
    uint4 vp1 = *(const uint4*)(vtbase + (size_t)(sr + 32) * TT + sd);

    float4v oacc[4] = {};   // [dt]: O(q=16wv+4*quad+r, d=16dt+lo), unnormalized
    float4v lsum = {};      // l(q=16wv+4*quad+r), replicated over lo

    for (int kt = 0; kt < TT / 128; ++kt) {
        __syncthreads();                       // prev tile fully consumed
        st8(&ks[sr][sd], kp0);
        st8(&ks[sr + 32][sd], kp1);
        st8(&vt[sr][sd], vp0);
        st8(&vt[sr + 32][sd], vp1);
        __syncthreads();

        // prefetch next tile (overlaps this tile's compute)
        const int kn = (kt < TT / 128 - 1 ? kt + 1 : kt) * 64;
        kp0 = *(const uint4*)(kbbase + (size_t)(kn + sr) * HD + sd);
        kp1 = *(const uint4*)(kbbase + (size_t)(kn + sr + 32) * HD + sd);
        vp0 = *(const uint4*)(vtbase + (size_t)sr * TT + kn + sd);
        vp1 = *(const uint4*)(vtbase + (size_t)(sr + 32) * TT + kn + sd);

        // bias for this tile (latency hides under QK MFMAs)
        float4 bcur[4];
        #pragma unroll
        for (int nt = 0; nt < 4; ++nt)
            bcur[nt] = *(const float4*)(brow + kt * 64 + nt * 16);

        // S^T = K Q^T
        float4v s[4] = {};
        #pragma unroll
        for (int kf = 0; kf < 2; ++kf) {
            #pragma unroll
            for (int nt = 0; nt < 4; ++nt) {
                short8v kfr = ld_frag(&ks[nt * 16 + lo][kf * 32 + quad * 8]);
                s[nt] = MFMA16(kfr, (kf ? aq1 : aq0), s[nt]);
            }
        }

        // exp (unshifted) -> wave-private ps (4 contiguous k per b64 write)
        #pragma unroll
        for (int nt = 0; nt < 4; ++nt) {
            float p0 = __expf(fmaf(s[nt][0], 0.125f, bcur[nt].x));
            float p1 = __expf(fmaf(s[nt][1], 0.125f, bcur[nt].y));
            float p2 = __expf(fmaf(s[nt][2], 0.125f, bcur[nt].z));
            float p3 = __expf(fmaf(s[nt][3], 0.125f, bcur[nt].w));
            short4v pv = { (short)f2bu(p0), (short)f2bu(p1),
                           (short)f2bu(p2), (short)f2bu(p3) };
            *(short4v*)&ps[wv][lo][nt * 16 + 4 * quad] = pv;
        }

        // O += P V ; l += P . 1   (A = ps row lo, b128)
        #pragma unroll
        for (int kf = 0; kf < 2; ++kf) {
            short8v ap = __builtin_bit_cast(short8v,
                *(const uint4*)&ps[wv][lo][kf * 32 + quad * 8]);
            lsum = MFMA16(ap, bones, lsum);
            #pragma unroll
            for (int dt = 0; dt < 4; ++dt) {
                short8v bv = ld_frag(&vt[dt * 16 + lo][kf * 32 + quad * 8]);
                oacc[dt] = MFMA16(ap, bv, oacc[dt]);
            }
        }
    }

    #pragma unroll
    for (int r = 0; r < 4; ++r) {
        int row = q0 + 16 * wv + 4 * quad + r;
        if (lo == 0)
            lws[((size_t)half * (BB * HH) + bh) * TT + row] = lsum[r];
        float* gp = opart + (((size_t)half * BB + b) * TT + row) * DDIM + h * HD + lo;
        #pragma unroll
        for (int dt = 0; dt < 4; ++dt)
            gp[dt * 16] = oacc[dt][r];
    }
}

// ---------------------------------------------------------------------------
// K2b: merge split-K partials: ob = (Oa + Ob) / (la + lb), bf16 out.
// ---------------------------------------------------------------------------
__global__ __launch_bounds__(256) void merge_kernel(
    const float* __restrict__ opart, const float* __restrict__ lws,
    u16* __restrict__ ob)
{
    size_t n = ((size_t)blockIdx.x * 256 + threadIdx.x) * 4;
    int d = (int)(n % DDIM);
    size_t rowi = n / DDIM;                 // b*TT + t
    int b = (int)(rowi >> 11), trow = (int)(rowi & (TT - 1));
    int bh = b * HH + d / HD;
    float la = lws[(size_t)bh * TT + trow] +
               lws[((size_t)(BB * HH) + bh) * TT + trow];
    float inv = 1.f / la;
    float4 oa = *(const float4*)(opart + n);
    float4 obp = *(const float4*)(opart + (size_t)BB * TT * DDIM + n);
    unsigned a0 = f2bu((oa.x + obp.x) * inv) | ((unsigned)f2bu((oa.y + obp.y) * inv) << 16);
    unsigned a1 = f2bu((oa.z + obp.z) * inv) | ((unsigned)f2bu((oa.w + obp.w) * inv) << 16);
    *(uint2*)(ob + n) = make_uint2(a0, a1);
}

// ---------------------------------------------------------------------------
// K3: out = O @ w_proj (MFMA), f32 output. Ping-pong + prefetch.
// ---------------------------------------------------------------------------
__global__ __launch_bounds__(256) void proj_kernel(
    const u16* __restrict__ o, const u16* __restrict__ wt, float* __restrict__ out)
{
    __shared__ __align__(16) u16 os[2][64][68];
    __shared__ __align__(16) u16 ws[2][64][68];
    const int t = threadIdx.x;
    const int wv = t >> 6, lane = t & 63, quad = lane >> 4, lo = lane & 15;
    const int r0 = blockIdx.y * 64, c0 = blockIdx.x * 64;
    const int sr = t >> 3, sd = (t & 7) * 8;

    st8(&os[0][sr][sd],      *(const uint4*)(o + (size_t)(r0 + sr) * DDIM + sd));
    st8(&os[0][sr + 32][sd], *(const uint4*)(o + (size_t)(r0 + sr + 32) * DDIM + sd));
    st8(&ws[0][sr][sd],      *(const uint4*)(wt + (size_t)(c0 + sr) * DDIM + sd));
    st8(&ws[0][sr + 32][sd], *(const uint4*)(wt + (size_t)(c0 + sr + 32) * DDIM + sd));
    __syncthreads();

    float4v acc[4] = {};
    for (int kk = 0; kk < 6; ++kk) {
        const int cur = kk & 1, nxt = cur ^ 1;
        const int kkn = (kk < 5 ? kk + 1 : 5) * 64;
        uint4 op0 = *(const uint4*)(o + (size_t)(r0 + sr) * DDIM + kkn + sd);
        uint4 op1 = *(const uint4*)(o + (size_t)(r0 + sr + 32) * DDIM + kkn + sd);
        uint4 wp0 = *(const uint4*)(wt + (size_t)(c0 + sr) * DDIM + kkn + sd);
        uint4 wp1 = *(const uint4*)(wt + (size_t)(c0 + sr + 32) * DDIM + kkn + sd);

        #pragma unroll
        for (int kf = 0; kf < 2; ++kf) {
            short8v a = ld_frag(&os[cur][16 * wv + lo][kf * 32 + quad * 8]);
            #pragma unroll
            for (int nt = 0; nt < 4; ++nt) {
                short8v bfr = ld_frag(&ws[cur][nt * 16 + lo][kf * 32 + quad * 8]);
                acc[nt] = MFMA16(a, bfr, acc[nt]);
            }
        }
        st8(&os[nxt][sr][sd], op0);
        st8(&os[nxt][sr + 32][sd], op1);
        st8(&ws[nxt][sr][sd], wp0);
        st8(&ws[nxt][sr + 32][sd], wp1);
        __syncthreads();
    }
    #pragma unroll
    for (int r = 0; r < 4; ++r) {
        float* gp = out + (size_t)(r0 + 16 * wv + 4 * quad + r) * DDIM + c0;
        #pragma unroll
        for (int nt = 0; nt < 4; ++nt)
            gp[nt * 16 + lo] = acc[nt][r];
    }
}

extern "C" void kernel_launch(void* const* d_in, const int* in_sizes, int n_in,
                              void* d_out, int out_size, void* d_ws, size_t ws_size,
                              hipStream_t stream) {
    const float* x     = (const float*)d_in[0];
    const float* bias  = (const float*)d_in[1];
    const float* cs    = (const float*)d_in[2];
    const float* sn    = (const float*)d_in[3];
    const float* wqkv  = (const float*)d_in[4];
    const float* wproj = (const float*)d_in[5];
    float* out = (float*)d_out;

    u16* wqkvT  = (u16*)d_ws;                         // [1152][384]
    u16* wprojT = wqkvT + (size_t)QKVC * DDIM;        // [384][384]
    u16* qb     = wprojT + (size_t)DDIM * DDIM;       // [bh][t][d]
    u16* kb     = qb + (size_t)BB * HH * TT * HD;     // [bh][t][d]
    u16* vtb    = kb + (size_t)BB * HH * TT * HD;     // [bh][d][t]
    u16* ob     = vtb + (size_t)BB * HH * TT * HD;    // [b][t][h*64+d]
    u16* xb     = ob + (size_t)BT * DDIM;             // [b*t][384] bf16 x
    float* opart = (float*)(xb + (size_t)BT * DDIM);  // [2][b][t][384] f32
    float* lws   = opart + (size_t)2 * BT * DDIM;     // [2][24][2048] f32
    // total ws use: ~84 MB

    prep_kernel<<<dim3(144 + BT * DDIM / 4096), 256, 0, stream>>>(
        wqkv, wproj, x, wqkvT, wprojT, xb);
    qkv_rope_kernel<<<dim3(QKVC / 64, BT / 64), 256, 0, stream>>>(
        xb, wqkvT, cs, sn, qb, kb, vtb);
    attn_kernel<<<dim3(BB * HH, TT / 64, 2), 256, 0, stream>>>(
        qb, kb, vtb, bias, opart, lws);
    merge_kernel<<<dim3(BT * DDIM / 1024), 256, 0, stream>>>(opart, lws, ob);
    proj_kernel<<<dim3(DDIM / 64, BT / 64), 256, 0, stream>>>(ob, wprojT, out);
}